// Round 3
// baseline (381.696 us; speedup 1.0000x reference)
//
#include <hip/hip_runtime.h>
#include <math.h>

#define K 8
#define D 256
#define BT 256
#define GRID_BLOCKS 512   // 2 blocks/CU x 256 CU, both kernels LDS-sized for exactly 2/CU
#define NSLOT 32
#define F_EPS 1e-12f
#define MOM 0.9f

#define SROWS 64          // k_source tile rows (full 256-dim rows)
#define TROWS 256         // k_target supertile rows (4 phases of 64 dims)

__device__ __forceinline__ float wave_allreduce_add(float v) {
#pragma unroll
    for (int m = 1; m < 64; m <<= 1) v += __shfl_xor(v, m, 64);
    return v;
}

// ---------------- Pass 1: source features -> cluster sums/counts ----------------
// Tile [64 rows][256 dims] f32 in LDS, 16B-chunk XOR swizzle (c ^= r&7) for bank-optimal
// b128 access in all three phases (stage-write, dot-read, scatter-read).
// Thread roles: dot phase (row = t&63, quarter q = wave), scatter phase (dim = t).
__global__ __launch_bounds__(BT, 2) void k_source(const float* __restrict__ src,
                                                  const float* __restrict__ P,
                                                  float* __restrict__ ws_sums,   // [NSLOT][K*D]
                                                  float* __restrict__ ws_cnts,   // [NSLOT][K]
                                                  int nrows) {
    __shared__ float tile[SROWS * D];          // 65,536 B
    __shared__ float scratch[4 * SROWS * 13];  // 13,312 B (13 = odd pad, conflict-free)
    __shared__ int   aidx[SROWS];
    __shared__ float ainvf[SROWS];
    // total 79,360 B -> exactly 2 blocks/CU

    const int t = threadIdx.x;
    const int lane = t & 63;
    const int w = t >> 6;
    const int row = lane;   // dot-phase row
    const int q = w;        // dim-quarter == wave id

    float acc[K];           // scatter accumulators: thread owns dim t
    float cnta[K];          // counts, used by wave 0 lanes only
#pragma unroll
    for (int k = 0; k < K; ++k) { acc[k] = 0.f; cnta[k] = 0.f; }

    const int nTiles = (nrows + SROWS - 1) / SROWS;

    float4 st[16];
    int tb = blockIdx.x;
    if (tb < nTiles) {
        // prologue: fully-coalesced load of tile tb (64 KB contiguous), 256 B/thread
#pragma unroll
        for (int j = 0; j < 16; ++j) {
            const int r = 4 * j + w;                      // row this float4 belongs to
            float4 v = make_float4(0.f, 0.f, 0.f, 0.f);
            if (tb * SROWS + r < nrows)
                v = *(const float4*)(src + (size_t)tb * (SROWS * D) + j * 1024 + t * 4);
            st[j] = v;
        }
    }

    for (; tb < nTiles; tb += gridDim.x) {
        __syncthreads();                     // previous tile fully consumed
        // staged regs -> LDS (swizzled); chunk within row = lane
#pragma unroll
        for (int j = 0; j < 16; ++j) {
            const int r = 4 * j + w;
            *(float4*)&tile[r * D + 4 * (lane ^ (r & 7))] = st[j];
        }
        __syncthreads();
        // issue next tile's loads now; they land during compute (T14 async-stage)
        const int tn = tb + gridDim.x;
        if (tn < nTiles) {
#pragma unroll
            for (int j = 0; j < 16; ++j) {
                const int r = 4 * j + w;
                float4 v = make_float4(0.f, 0.f, 0.f, 0.f);
                if (tn * SROWS + r < nrows)
                    v = *(const float4*)(src + (size_t)tn * (SROWS * D) + j * 1024 + t * 4);
                st[j] = v;
            }
        }

        // ---- dot phase: row `row`, dims [q*64, q*64+64) to registers ----
        float4 x[16];
#pragma unroll
        for (int i = 0; i < 16; ++i)
            x[i] = *(const float4*)&tile[row * D + 4 * ((16 * q + i) ^ (row & 7))];
        float nrm = 0.f;
#pragma unroll
        for (int i = 0; i < 16; ++i)
            nrm += x[i].x * x[i].x + x[i].y * x[i].y + x[i].z * x[i].z + x[i].w * x[i].w;
        const int qu = __builtin_amdgcn_readfirstlane(q);   // wave-uniform -> scalar proto loads
        float dots[K];
#pragma unroll
        for (int k = 0; k < K; ++k) {
            const float* pk = P + k * D + qu * 64;
            float dk = 0.f;
#pragma unroll
            for (int i = 0; i < 16; ++i) {
                const float4 p = *(const float4*)(pk + 4 * i);
                dk += x[i].x * p.x + x[i].y * p.y + x[i].z * p.z + x[i].w * p.w;
            }
            dots[k] = dk;
        }
        // partials to scratch
#pragma unroll
        for (int k = 0; k < K; ++k) scratch[(q * SROWS + row) * 13 + k] = dots[k];
        scratch[(q * SROWS + row) * 13 + 8] = nrm;
        __syncthreads();

        // ---- finish (wave 0, lane = row): argmax + inv-norm ----
        if (w == 0) {
            float dsum[9];
#pragma unroll
            for (int j = 0; j < 9; ++j)
                dsum[j] = scratch[(0 * SROWS + lane) * 13 + j]
                        + scratch[(1 * SROWS + lane) * 13 + j]
                        + scratch[(2 * SROWS + lane) * 13 + j]
                        + scratch[(3 * SROWS + lane) * 13 + j];
            const float inv = 1.0f / fmaxf(sqrtf(dsum[8]), F_EPS);
            int a = 0; float m = dsum[0];
#pragma unroll
            for (int k = 1; k < K; ++k) if (dsum[k] > m) { m = dsum[k]; a = k; }  // first-max ties
            const bool valid = (tb * SROWS + lane) < nrows;
            aidx[lane] = a;
            ainvf[lane] = valid ? inv : 0.f;   // invalid rows contribute 0 to sums
            if (valid) {
#pragma unroll
                for (int k = 0; k < K; ++k) cnta[k] += (a == k) ? 1.f : 0.f;
            }
        }
        __syncthreads();

        // ---- scatter: thread owns dim t; branchless accumulate (no runtime reg index) ----
#pragma unroll 4
        for (int r = 0; r < SROWS; ++r) {
            const float iv = ainvf[r];                        // LDS broadcast
            const int a = aidx[r];                            // LDS broadcast
            const float xv = tile[r * D + 4 * ((t >> 2) ^ (r & 7)) + (t & 3)] * iv;
#pragma unroll
            for (int k = 0; k < K; ++k) acc[k] += (a == k) ? xv : 0.f;
        }
    }

    // ---- flush ----
    const int slot = blockIdx.x & (NSLOT - 1);
    float* gs = ws_sums + (size_t)slot * (K * D);
#pragma unroll
    for (int k = 0; k < K; ++k) unsafeAtomicAdd(&gs[k * D + t], acc[k]);   // coalesced per k
    if (w == 0) {
#pragma unroll
        for (int k = 0; k < K; ++k) {
            const float c = wave_allreduce_add(cnta[k]);
            if (lane == 0) unsafeAtomicAdd(&ws_cnts[slot * K + k], c);
        }
    }
}

// ---------------- Prototype momentum update + renormalize (1 block, wave per proto) ----------------
__global__ __launch_bounds__(512) void k_protos(const float* __restrict__ sums_slots,
                                                const float* __restrict__ cnt_slots,
                                                const float* __restrict__ protos_in,
                                                float* __restrict__ protos_out) {
    const int t = threadIdx.x;
    const int k = t >> 6;
    const int lane = t & 63;

    float c = 0.0f;
    for (int s = 0; s < NSLOT; ++s) c += cnt_slots[s * K + k];

    float4 sm = make_float4(0.f, 0.f, 0.f, 0.f);
    for (int s = 0; s < NSLOT; ++s) {
        float4 v = *(const float4*)(sums_slots + (size_t)s * (K * D) + k * D + lane * 4);
        sm.x += v.x; sm.y += v.y; sm.z += v.z; sm.w += v.w;
    }
    const float cc = fmaxf(c, 1.0f);
    float4 m = make_float4(sm.x / cc, sm.y / cc, sm.z / cc, sm.w / cc);
    float nr = wave_allreduce_add(m.x * m.x + m.y * m.y + m.z * m.z + m.w * m.w);
    const float s1 = 1.0f / fmaxf(sqrtf(nr), F_EPS);
    float4 pin = *(const float4*)(protos_in + k * D + lane * 4);
    float4 upd;
    if (c > 0.0f) {
        upd = make_float4(MOM * pin.x + (1.0f - MOM) * m.x * s1,
                          MOM * pin.y + (1.0f - MOM) * m.y * s1,
                          MOM * pin.z + (1.0f - MOM) * m.z * s1,
                          MOM * pin.w + (1.0f - MOM) * m.w * s1);
    } else {
        upd = pin;
    }
    float n2 = wave_allreduce_add(upd.x * upd.x + upd.y * upd.y + upd.z * upd.z + upd.w * upd.w);
    const float s2 = 1.0f / fmaxf(sqrtf(n2), F_EPS);
    *(float4*)(protos_out + k * D + lane * 4) =
        make_float4(upd.x * s2, upd.y * s2, upd.z * s2, upd.w * s2);
}

// ---------------- Pass 2: target features -> mean(1 - max cos) ----------------
// Supertile = 256 rows; 4 phases stage [256 rows][64-dim quarter] f32 (swizzled).
// Thread t owns row t: after 4 phases it holds all 8 dots + norm in registers.
// Zero cross-lane ops per tile; one atomic per block.
__global__ __launch_bounds__(BT, 2) void k_target(const float* __restrict__ tgt,
                                                  const float* __restrict__ P,
                                                  float* __restrict__ loss_slots,
                                                  int nrows) {
    __shared__ float tile[TROWS * 64];   // 65,536 B -> 2 blocks/CU
    __shared__ float red[4];
    const int t = threadIdx.x;
    const int lane = t & 63;
    const int w = t >> 6;
    const int srow0 = t >> 4;   // staging: 16 rows apart
    const int schunk = t & 15;  // 16B chunk within the 64-dim quarter

    float lacc = 0.f;
    const int nSuper = (nrows + TROWS - 1) / TROWS;
    for (int sb = blockIdx.x; sb < nSuper; sb += gridDim.x) {
        const int rbase = sb * TROWS;
        float dots[K]; float nrm = 0.f;
#pragma unroll
        for (int k = 0; k < K; ++k) dots[k] = 0.f;

        float4 st[16];
        // prologue: phase-0 loads (4 contiguous 256B segments per wave instr, full lines)
#pragma unroll
        for (int j = 0; j < 16; ++j) {
            const int r = srow0 + 16 * j;
            float4 v = make_float4(0.f, 0.f, 0.f, 0.f);
            if (rbase + r < nrows)
                v = *(const float4*)(tgt + (size_t)(rbase + r) * D + schunk * 4);
            st[j] = v;
        }
#pragma unroll
        for (int qp = 0; qp < 4; ++qp) {
            __syncthreads();              // previous phase's readers done
#pragma unroll
            for (int j = 0; j < 16; ++j) {
                const int r = srow0 + 16 * j;
                *(float4*)&tile[r * 64 + 4 * (schunk ^ (r & 7))] = st[j];
            }
            __syncthreads();
            if (qp < 3) {                 // issue next phase's loads; land during compute
#pragma unroll
                for (int j = 0; j < 16; ++j) {
                    const int r = srow0 + 16 * j;
                    float4 v = make_float4(0.f, 0.f, 0.f, 0.f);
                    if (rbase + r < nrows)
                        v = *(const float4*)(tgt + (size_t)(rbase + r) * D + (qp + 1) * 64 + schunk * 4);
                    st[j] = v;
                }
            }
            // compute: thread t owns row t
            float4 x[16];
#pragma unroll
            for (int i = 0; i < 16; ++i)
                x[i] = *(const float4*)&tile[t * 64 + 4 * (i ^ (t & 7))];
#pragma unroll
            for (int i = 0; i < 16; ++i)
                nrm += x[i].x * x[i].x + x[i].y * x[i].y + x[i].z * x[i].z + x[i].w * x[i].w;
#pragma unroll
            for (int k = 0; k < K; ++k) {
                const float* pk = P + k * D + qp * 64;    // fully uniform -> s_load
                float dk = 0.f;
#pragma unroll
                for (int i = 0; i < 16; ++i) {
                    const float4 p = *(const float4*)(pk + 4 * i);
                    dk += x[i].x * p.x + x[i].y * p.y + x[i].z * p.z + x[i].w * p.w;
                }
                dots[k] += dk;
            }
        }
        // finish entirely in-lane
        if (rbase + t < nrows) {
            const float inv = 1.0f / fmaxf(sqrtf(nrm), F_EPS);
            float m = dots[0];
#pragma unroll
            for (int k = 1; k < K; ++k) m = fmaxf(m, dots[k]);
            lacc += 1.0f - m * inv;
        }
    }
    // block reduce + single atomic
    lacc = wave_allreduce_add(lacc);
    if (lane == 0) red[w] = lacc;
    __syncthreads();
    if (t == 0)
        unsafeAtomicAdd(&loss_slots[blockIdx.x & (NSLOT - 1)], red[0] + red[1] + red[2] + red[3]);
}

__global__ void k_loss(const float* __restrict__ loss_slots, float* __restrict__ out, float invN) {
    float v = (threadIdx.x < NSLOT) ? loss_slots[threadIdx.x] : 0.0f;
    v = wave_allreduce_add(v);
    if (threadIdx.x == 0) out[0] = v * invN;
}

extern "C" void kernel_launch(void* const* d_in, const int* in_sizes, int n_in,
                              void* d_out, int out_size, void* d_ws, size_t ws_size,
                              hipStream_t stream) {
    const float* src = (const float*)d_in[0];
    const float* tgt = (const float*)d_in[1];
    const float* protos = (const float*)d_in[2];
    float* out = (float*)d_out;
    float* ws = (float*)d_ws;

    const int Ns = in_sizes[0] / D;
    const int Nt = in_sizes[1] / D;

    float* ws_sums = ws;                                 // NSLOT*K*D
    float* ws_cnts = ws_sums + NSLOT * K * D;            // NSLOT*K
    float* ws_loss = ws_cnts + NSLOT * K;                // NSLOT
    float* ws_protos = ws_loss + NSLOT;                  // K*D
    const size_t zero_bytes = (size_t)(NSLOT * K * D + NSLOT * K + NSLOT) * sizeof(float);
    hipMemsetAsync(d_ws, 0, zero_bytes, stream);

    const int nTilesS = (Ns + SROWS - 1) / SROWS;
    const int nSuperT = (Nt + TROWS - 1) / TROWS;
    const int gridS = (nTilesS < GRID_BLOCKS) ? nTilesS : GRID_BLOCKS;
    const int gridT = (nSuperT < GRID_BLOCKS) ? nSuperT : GRID_BLOCKS;

    k_source<<<gridS, BT, 0, stream>>>(src, protos, ws_sums, ws_cnts, Ns);
    k_protos<<<1, 512, 0, stream>>>(ws_sums, ws_cnts, protos, ws_protos);
    k_target<<<gridT, BT, 0, stream>>>(tgt, ws_protos, ws_loss, Nt);
    k_loss<<<1, 64, 0, stream>>>(ws_loss, out, 1.0f / (float)Nt);
}